// Round 1
// baseline (83.342 us; speedup 1.0000x reference)
//
#include <hip/hip_runtime.h>

// Problem shape (fixed by the reference setup_inputs)
constexpr int B  = 4;
constexpr int H  = 16;
constexpr int S  = 4096;
constexpr int D  = 128;
constexpr int BH = B * H;          // 64
constexpr int CHUNKS = 128;        // chunks along S
constexpr int L  = S / CHUNKS;     // 32 elements per chunk
constexpr int D4 = D / 4;          // 32 float4 lanes per row

// ---------------------------------------------------------------------------
// Phase 1: per-chunk carry  b_c[d] = sum_{i<L} gamma^{L-1-i} x[cL+i, d]
// One thread owns one (bh, c, d4) float4 column of a chunk.
// Total threads = BH*CHUNKS*D4 = 262144 -> 1024 blocks x 256.
// ---------------------------------------------------------------------------
__global__ __launch_bounds__(256) void dc_phase1(const float4* __restrict__ x,
                                                 const float* __restrict__ gamma,
                                                 float4* __restrict__ ws) {
    const int tid  = blockIdx.x * 256 + threadIdx.x;
    const int l    = tid & (D4 - 1);        // float4 index within d
    const int unit = tid >> 5;              // (bh, c)
    const int c    = unit % CHUNKS;
    const int bh   = unit / CHUNKS;
    const float g  = gamma[bh % H];

    const float4* p = x + (size_t)(bh * S + c * L) * D4 + l;
    float4 carry = {0.f, 0.f, 0.f, 0.f};
    #pragma unroll 8
    for (int i = 0; i < L; ++i) {
        float4 v = p[(size_t)i * D4];
        carry.x = fmaf(g, carry.x, v.x);
        carry.y = fmaf(g, carry.y, v.y);
        carry.z = fmaf(g, carry.z, v.z);
        carry.w = fmaf(g, carry.w, v.w);
    }
    ws[(size_t)unit * D4 + l] = carry;
}

// ---------------------------------------------------------------------------
// Phase 2: exclusive scan over chunk carries per (bh, d) column.
//   P_0 = 0 ; P_{c+1} = gamma^L * P_c + b_c   (write exclusive prefix in place)
// Threads = BH*D = 8192 -> 32 blocks x 256.
// ---------------------------------------------------------------------------
__global__ __launch_bounds__(256) void dc_phase2(const float* __restrict__ gamma,
                                                 float* __restrict__ ws) {
    const int tid = blockIdx.x * 256 + threadIdx.x;   // [0, BH*D)
    const int d   = tid % D;
    const int bh  = tid / D;
    const float g = gamma[bh % H];

    // gamma^L, L = 32 = 2^5 : five exact squarings
    float gL = g;
    #pragma unroll
    for (int k = 0; k < 5; ++k) gL *= gL;

    float* base = ws + (size_t)bh * CHUNKS * D + d;
    float P = 0.f;
    #pragma unroll 4
    for (int c = 0; c < CHUNKS; ++c) {
        float bv = base[(size_t)c * D];
        base[(size_t)c * D] = P;
        P = fmaf(gL, P, bv);
    }
}

// ---------------------------------------------------------------------------
// Phase 3: seed each chunk with its exclusive prefix, run the local
// recurrence, write the output.  Same mapping as phase 1.
// ---------------------------------------------------------------------------
__global__ __launch_bounds__(256) void dc_phase3(const float4* __restrict__ x,
                                                 const float* __restrict__ gamma,
                                                 const float4* __restrict__ ws,
                                                 float4* __restrict__ y) {
    const int tid  = blockIdx.x * 256 + threadIdx.x;
    const int l    = tid & (D4 - 1);
    const int unit = tid >> 5;
    const int c    = unit % CHUNKS;
    const int bh   = unit / CHUNKS;
    const float g  = gamma[bh % H];

    const size_t off = (size_t)(bh * S + c * L) * D4 + l;
    const float4* p  = x + off;
    float4*       q  = y + off;

    float4 carry = ws[(size_t)unit * D4 + l];
    #pragma unroll 8
    for (int i = 0; i < L; ++i) {
        float4 v = p[(size_t)i * D4];
        carry.x = fmaf(g, carry.x, v.x);
        carry.y = fmaf(g, carry.y, v.y);
        carry.z = fmaf(g, carry.z, v.z);
        carry.w = fmaf(g, carry.w, v.w);
        q[(size_t)i * D4] = carry;
    }
}

extern "C" void kernel_launch(void* const* d_in, const int* in_sizes, int n_in,
                              void* d_out, int out_size, void* d_ws, size_t ws_size,
                              hipStream_t stream) {
    const float*  x     = (const float*)d_in[0];   // (B,H,S,D) fp32
    const float*  gamma = (const float*)d_in[1];   // (H,) fp32
    float*        y     = (float*)d_out;           // (B,H,S,D) fp32
    float*        ws    = (float*)d_ws;            // needs BH*CHUNKS*D*4 = 4 MiB

    constexpr int UNITS   = BH * CHUNKS;           // 8192
    constexpr int THREADS = UNITS * D4;            // 262144
    constexpr int BLOCKS13 = THREADS / 256;        // 1024
    constexpr int BLOCKS2  = (BH * D) / 256;       // 32

    dc_phase1<<<BLOCKS13, 256, 0, stream>>>((const float4*)x, gamma, (float4*)ws);
    dc_phase2<<<BLOCKS2, 256, 0, stream>>>(gamma, ws);
    dc_phase3<<<BLOCKS13, 256, 0, stream>>>((const float4*)x, gamma,
                                            (const float4*)ws, (float4*)y);
}